// Round 3
// baseline (240.330 us; speedup 1.0000x reference)
//
#include <hip/hip_runtime.h>

typedef float f32x4 __attribute__((ext_vector_type(4)));

#define MFMA8(a, b, c) __builtin_amdgcn_mfma_f32_16x16x32_fp8_fp8((long)(a), (long)(b), (c), 0, 0, 0)

__device__ __forceinline__ unsigned char f2fp8(float v) {
    int pk = __builtin_amdgcn_cvt_pk_fp8_f32(v, v, 0, false);
    return (unsigned char)(pk & 0xff);
}
__device__ __forceinline__ long packrow8(const float* p) {
    f32x4 a = *(const f32x4*)(p);
    f32x4 b = *(const f32x4*)(p + 4);
    int lo = __builtin_amdgcn_cvt_pk_fp8_f32(a.x, a.y, 0, false);
    lo = __builtin_amdgcn_cvt_pk_fp8_f32(a.z, a.w, lo, true);
    int hi = __builtin_amdgcn_cvt_pk_fp8_f32(b.x, b.y, 0, false);
    hi = __builtin_amdgcn_cvt_pk_fp8_f32(b.z, b.w, hi, true);
    return (long)(((unsigned long)(unsigned int)hi << 32) | (unsigned int)lo);
}

// ---------------- Kernel 1: LayerNorm partial sums ----------------
__global__ __launch_bounds__(256) void k_ln_part(const float* __restrict__ x,
                                                 float* __restrict__ part) {
    const int chunk = blockIdx.x, b = blockIdx.y, t = threadIdx.x;
    const float4* p = (const float4*)(x + b * 262144 + chunk * 16384);
    float s = 0.f, ss = 0.f;
    #pragma unroll
    for (int r = 0; r < 16; ++r) {
        float4 v = p[r * 256 + t];
        s  += v.x + v.y + v.z + v.w;
        ss += v.x * v.x + v.y * v.y + v.z * v.z + v.w * v.w;
    }
    #pragma unroll
    for (int off = 32; off > 0; off >>= 1) {
        s  += __shfl_down(s, off);
        ss += __shfl_down(ss, off);
    }
    __shared__ float sm[8];
    int wv = t >> 6;
    if ((t & 63) == 0) { sm[wv * 2] = s; sm[wv * 2 + 1] = ss; }
    __syncthreads();
    if (t == 0) {
        float S  = sm[0] + sm[2] + sm[4] + sm[6];
        float SS = sm[1] + sm[3] + sm[5] + sm[7];
        part[(b * 16 + chunk) * 2]     = S;
        part[(b * 16 + chunk) * 2 + 1] = SS;
    }
}

// ---------------- Kernel 2: LayerNorm finalize ----------------
__global__ void k_ln_fin(const float* __restrict__ part, float* __restrict__ stats) {
    int t = threadIdx.x;
    if (t < 32) {
        float S = 0.f, SS = 0.f;
        for (int k = 0; k < 16; ++k) {
            S  += part[(t * 16 + k) * 2];
            SS += part[(t * 16 + k) * 2 + 1];
        }
        const float inv = 1.0f / 262144.0f;
        float mu  = S * inv;
        float var = SS * inv - mu * mu;
        stats[t * 2]     = mu;
        stats[t * 2 + 1] = rsqrtf(var + 1e-5f);
    }
}

// ---------------- Kernel 3: fused conv + K/V + attention + proj (fp8 MFMA) ----------------
// grid (8 tile-groups, 32 batches), 512 threads = 8 waves.
// LDS map (bytes): Kf8 [256][72] @0; Vt [64][264] @18432; union @35328:
//   build-phase: Y [256][72] fp8
//   tile-phase : XS [64][72] @+0 | QF [64][72] @+4608 | PS 8x[16][40] @+9216 | TS [64][72] @+14336
__global__ __launch_bounds__(512) void k_fused(
    const float* __restrict__ x, const float* __restrict__ Wdw, const float* __restrict__ bdw,
    const float* __restrict__ Wq, const float* __restrict__ bq,
    const float* __restrict__ Wk, const float* __restrict__ bk,
    const float* __restrict__ Wv, const float* __restrict__ bv,
    const float* __restrict__ Wo, const float* __restrict__ bo,
    const float* __restrict__ Bb, const float* __restrict__ stats,
    float* __restrict__ outp)
{
    __shared__ long smem8[6784];                 // 54272 B
    unsigned char* S = (unsigned char*)smem8;
    unsigned char* Kf = S;                        // [256][72]
    unsigned char* Vt = S + 18432;                // [64][264]
    unsigned char* Y  = S + 35328;                // [256][72]
    unsigned char* XS = S + 35328;                // [64][72]
    unsigned char* QF = S + 35328 + 4608;         // [64][72]
    unsigned char* TS = S + 35328 + 14336;        // [64][72]

    const int tg = blockIdx.x, b = blockIdx.y;
    const int t = threadIdx.x, w = t >> 6, lane = t & 63;
    const int quad = lane >> 4, l = lane & 15;
    unsigned char* PS = S + 35328 + 9216 + w * 640;   // [16][40] per wave

    const float mu = stats[2 * b], rstd = stats[2 * b + 1];
    const float* xb = x + b * 262144;
    const float SCALE = 0.17677669529663687f;

    // ---- preload weight fragments (fp8 packed, resident in VGPRs) ----
    long wkF[8], wvF[8];           // wkF: B-op [et][step]; wvF: A-op [dct][step]
    #pragma unroll
    for (int e4 = 0; e4 < 4; ++e4)
        #pragma unroll
        for (int st = 0; st < 2; ++st) {
            wkF[e4 * 2 + st] = packrow8(Wk + (e4 * 16 + l) * 64 + st * 32 + quad * 8);
            wvF[e4 * 2 + st] = packrow8(Wv + (e4 * 16 + l) * 64 + st * 32 + quad * 8);
        }
    const int rtq = w >> 1, ct0 = (w & 1) * 2;    // Q-gen / out-proj tile assignment
    long wqF[4], woF[4];
    #pragma unroll
    for (int i = 0; i < 2; ++i)
        #pragma unroll
        for (int st = 0; st < 2; ++st) {
            wqF[i * 2 + st] = packrow8(Wq + ((ct0 + i) * 16 + l) * 64 + st * 32 + quad * 8);
            woF[i * 2 + st] = packrow8(Wo + ((ct0 + i) * 16 + l) * 64 + st * 32 + quad * 8);
        }
    float bkr[4], bvr[4][4], bqr[2], bor[2];
    #pragma unroll
    for (int e4 = 0; e4 < 4; ++e4) bkr[e4] = bk[e4 * 16 + l];
    #pragma unroll
    for (int d4 = 0; d4 < 4; ++d4)
        #pragma unroll
        for (int r = 0; r < 4; ++r) bvr[d4][r] = bv[d4 * 16 + quad * 4 + r];
    #pragma unroll
    for (int i = 0; i < 2; ++i) { bqr[i] = bq[(ct0 + i) * 16 + l]; bor[i] = bo[(ct0 + i) * 16 + l]; }

    // ---- depthwise conv -> Y fp8 [m][c] (wave w owns channels 8w..8w+8) ----
    {
        const int s2l = lane & 3, mjl = lane >> 2;    // x col = 4*mj + s2 == lane
        for (int ci = 0; ci < 8; ++ci) {
            int c = w * 8 + ci;
            float wd0 = Wdw[c * 16 + 0 + s2l];
            float wd1 = Wdw[c * 16 + 4 + s2l];
            float wd2 = Wdw[c * 16 + 8 + s2l];
            float wd3 = Wdw[c * 16 + 12 + s2l];
            float bdc = bdw[c];
            #pragma unroll 4
            for (int mi = 0; mi < 16; ++mi) {
                const float* xr = xb + c * 4096 + mi * 256;
                float acc = xr[lane] * wd0;
                acc = fmaf(xr[64 + lane],  wd1, acc);
                acc = fmaf(xr[128 + lane], wd2, acc);
                acc = fmaf(xr[192 + lane], wd3, acc);
                acc += __shfl_xor(acc, 1);
                acc += __shfl_xor(acc, 2);
                if (s2l == 0) Y[(mi * 16 + mjl) * 72 + c] = f2fp8(acc + bdc);
            }
        }
    }
    __syncthreads();

    // ---- K/V projections via MFMA (wave w owns m-tiles 2w, 2w+1) ----
    #pragma unroll
    for (int i = 0; i < 2; ++i) {
        int rt = w * 2 + i;
        long ya0 = *(const long*)(Y + (rt * 16 + l) * 72 + quad * 8);
        long ya1 = *(const long*)(Y + (rt * 16 + l) * 72 + 32 + quad * 8);
        #pragma unroll
        for (int e4 = 0; e4 < 4; ++e4) {                 // K[m][e] = y . Wk^T + bk
            f32x4 c = { bkr[e4], bkr[e4], bkr[e4], bkr[e4] };
            c = MFMA8(ya0, wkF[e4 * 2 + 0], c);
            c = MFMA8(ya1, wkF[e4 * 2 + 1], c);
            unsigned char* kd = Kf + (rt * 16 + quad * 4) * 72 + e4 * 16 + l;
            #pragma unroll
            for (int r = 0; r < 4; ++r) kd[r * 72] = f2fp8(c[r]);
        }
        #pragma unroll
        for (int d4 = 0; d4 < 4; ++d4) {                 // Vt[dc][m] = Wv . y^T + bv
            f32x4 c = { bvr[d4][0], bvr[d4][1], bvr[d4][2], bvr[d4][3] };
            c = MFMA8(wvF[d4 * 2 + 0], ya0, c);
            c = MFMA8(wvF[d4 * 2 + 1], ya1, c);
            unsigned char* vd = Vt + (d4 * 16 + quad * 4) * 264 + rt * 16 + l;
            #pragma unroll
            for (int r = 0; r < 4; ++r) vd[r * 264] = f2fp8(c[r]);
        }
    }
    __syncthreads();

    const int h = w & 1, nq = w >> 1;                    // attention wave mapping

    for (int tile = 0; tile < 8; ++tile) {
        const int tidx = tg * 8 + tile, n0 = tidx * 64;

        // stage normalized x tile -> XS[n][c] fp8
        for (int ci = 0; ci < 8; ++ci) {
            int c = w * 8 + ci;
            float v = (xb[c * 4096 + n0 + lane] - mu) * rstd;
            XS[lane * 72 + c] = f2fp8(v);
        }
        __syncthreads();

        // Q-gen via MFMA: q[n][e] = xn . Wq^T + bq  -> QF fp8
        {
            long xa0 = *(const long*)(XS + (rtq * 16 + l) * 72 + quad * 8);
            long xa1 = *(const long*)(XS + (rtq * 16 + l) * 72 + 32 + quad * 8);
            #pragma unroll
            for (int i = 0; i < 2; ++i) {
                f32x4 c = { bqr[i], bqr[i], bqr[i], bqr[i] };
                c = MFMA8(xa0, wqF[i * 2 + 0], c);
                c = MFMA8(xa1, wqF[i * 2 + 1], c);
                unsigned char* qd = QF + (rtq * 16 + quad * 4) * 72 + (ct0 + i) * 16 + l;
                #pragma unroll
                for (int r = 0; r < 4; ++r) qd[r * 72] = f2fp8(c[r]);
            }
        }
        __syncthreads();

        // ---- attention (wave-local): wave = (h, nq); 16 q-rows, all 256 keys ----
        long qa = *(const long*)(QF + (nq * 16 + l) * 72 + h * 32 + quad * 8);
        f32x4 O0 = { 0, 0, 0, 0 }, O1 = { 0, 0, 0, 0 };
        float Lp[4] = { 0, 0, 0, 0 };
        const float* Bbase = Bb + h * 1048576 + (n0 + nq * 16 + quad * 4) * 256;

        #pragma unroll 2
        for (int mc = 0; mc < 8; ++mc) {
            #pragma unroll
            for (int sub = 0; sub < 2; ++sub) {
                int mt = mc * 2 + sub;
                long kb = *(const long*)(Kf + (mt * 16 + l) * 72 + h * 32 + quad * 8);
                f32x4 sc = { 0, 0, 0, 0 };
                sc = MFMA8(qa, kb, sc);
                unsigned char* pw = PS + (quad * 4) * 40 + sub * 16 + l;
                #pragma unroll
                for (int r = 0; r < 4; ++r) {
                    float p = __expf(fmaf(sc[r], SCALE, Bbase[r * 256 + mt * 16 + l]));
                    Lp[r] += p;
                    pw[r * 40] = f2fp8(p);
                }
            }
            long pa  = *(const long*)(PS + l * 40 + quad * 8);
            long vb0 = *(const long*)(Vt + (h * 32 + l) * 264 + mc * 32 + quad * 8);
            long vb1 = *(const long*)(Vt + (h * 32 + 16 + l) * 264 + mc * 32 + quad * 8);
            O0 = MFMA8(pa, vb0, O0);
            O1 = MFMA8(pa, vb1, O1);
        }
        #pragma unroll
        for (int r = 0; r < 4; ++r) {
            #pragma unroll
            for (int d = 1; d < 16; d <<= 1) Lp[r] += __shfl_xor(Lp[r], d);
        }
        {
            unsigned char* td = TS + (nq * 16 + quad * 4) * 72 + h * 32 + l;
            #pragma unroll
            for (int r = 0; r < 4; ++r) {
                float inv = 1.0f / Lp[r];
                td[r * 72]      = f2fp8(O0[r] * inv);
                td[r * 72 + 16] = f2fp8(O1[r] * inv);
            }
        }
        __syncthreads();

        // ---- out-proj via MFMA + bias + residual ----
        {
            long ta0 = *(const long*)(TS + (rtq * 16 + l) * 72 + quad * 8);
            long ta1 = *(const long*)(TS + (rtq * 16 + l) * 72 + 32 + quad * 8);
            float* ob = outp + b * 262144 + tidx * 4096;
            const float* xr2 = xb + tidx * 4096;
            #pragma unroll
            for (int i = 0; i < 2; ++i) {
                f32x4 c = { bor[i], bor[i], bor[i], bor[i] };
                c = MFMA8(ta0, woF[i * 2 + 0], c);
                c = MFMA8(ta1, woF[i * 2 + 1], c);
                #pragma unroll
                for (int r = 0; r < 4; ++r) {
                    int off = (rtq * 16 + quad * 4 + r) * 64 + (ct0 + i) * 16 + l;
                    ob[off] = c[r] + xr2[off];
                }
            }
        }
        __syncthreads();
    }
}

extern "C" void kernel_launch(void* const* d_in, const int* in_sizes, int n_in,
                              void* d_out, int out_size, void* d_ws, size_t ws_size,
                              hipStream_t stream) {
    (void)in_sizes; (void)n_in; (void)out_size; (void)ws_size;
    const float* x   = (const float*)d_in[0];
    const float* Wdw = (const float*)d_in[1];
    const float* bdw = (const float*)d_in[2];
    const float* Wq  = (const float*)d_in[3];
    const float* bq  = (const float*)d_in[4];
    const float* Wk  = (const float*)d_in[5];
    const float* bk  = (const float*)d_in[6];
    const float* Wv  = (const float*)d_in[7];
    const float* bv  = (const float*)d_in[8];
    const float* Wo  = (const float*)d_in[9];
    const float* bo  = (const float*)d_in[10];
    const float* Bb  = (const float*)d_in[11];
    float* outp = (float*)d_out;

    float* ws    = (float*)d_ws;
    float* part  = ws;            // 1024 f32
    float* stats = ws + 1024;     // 64 f32   (total ws use: 4352 B)

    k_ln_part<<<dim3(16, 32), 256, 0, stream>>>(x, part);
    k_ln_fin<<<1, 64, 0, stream>>>(part, stats);
    k_fused<<<dim3(8, 32), 512, 0, stream>>>(x, Wdw, bdw, Wq, bq, Wk, bk, Wv, bv,
                                             Wo, bo, Bb, stats, outp);
}

// Round 4
// 166.674 us; speedup vs baseline: 1.4419x; 1.4419x over previous
//
#include <hip/hip_runtime.h>

typedef float f32x4 __attribute__((ext_vector_type(4)));

#define MFMA8(a, b, c) __builtin_amdgcn_mfma_f32_16x16x32_fp8_fp8((long)(a), (long)(b), (c), 0, 0, 0)

__device__ __forceinline__ unsigned char f2fp8(float v) {
    int pk = __builtin_amdgcn_cvt_pk_fp8_f32(v, v, 0, false);
    return (unsigned char)(pk & 0xff);
}
__device__ __forceinline__ long packrow8(const float* p) {
    f32x4 a = *(const f32x4*)(p);
    f32x4 b = *(const f32x4*)(p + 4);
    int lo = __builtin_amdgcn_cvt_pk_fp8_f32(a.x, a.y, 0, false);
    lo = __builtin_amdgcn_cvt_pk_fp8_f32(a.z, a.w, lo, true);
    int hi = __builtin_amdgcn_cvt_pk_fp8_f32(b.x, b.y, 0, false);
    hi = __builtin_amdgcn_cvt_pk_fp8_f32(b.z, b.w, hi, true);
    return (long)(((unsigned long)(unsigned int)hi << 32) | (unsigned int)lo);
}

// ---------------- Kernel 1: LayerNorm partial sums ----------------
__global__ __launch_bounds__(256) void k_ln_part(const float* __restrict__ x,
                                                 float* __restrict__ part) {
    const int chunk = blockIdx.x, b = blockIdx.y, t = threadIdx.x;
    const float4* p = (const float4*)(x + b * 262144 + chunk * 16384);
    float s = 0.f, ss = 0.f;
    #pragma unroll
    for (int r = 0; r < 16; ++r) {
        float4 v = p[r * 256 + t];
        s  += v.x + v.y + v.z + v.w;
        ss += v.x * v.x + v.y * v.y + v.z * v.z + v.w * v.w;
    }
    #pragma unroll
    for (int off = 32; off > 0; off >>= 1) {
        s  += __shfl_down(s, off);
        ss += __shfl_down(ss, off);
    }
    __shared__ float sm[8];
    int wv = t >> 6;
    if ((t & 63) == 0) { sm[wv * 2] = s; sm[wv * 2 + 1] = ss; }
    __syncthreads();
    if (t == 0) {
        float S  = sm[0] + sm[2] + sm[4] + sm[6];
        float SS = sm[1] + sm[3] + sm[5] + sm[7];
        part[(b * 16 + chunk) * 2]     = S;
        part[(b * 16 + chunk) * 2 + 1] = SS;
    }
}

// ---------------- Kernel 2: LayerNorm finalize ----------------
__global__ void k_ln_fin(const float* __restrict__ part, float* __restrict__ stats) {
    int t = threadIdx.x;
    if (t < 32) {
        float S = 0.f, SS = 0.f;
        for (int k = 0; k < 16; ++k) {
            S  += part[(t * 16 + k) * 2];
            SS += part[(t * 16 + k) * 2 + 1];
        }
        const float inv = 1.0f / 262144.0f;
        float mu  = S * inv;
        float var = SS * inv - mu * mu;
        stats[t * 2]     = mu;
        stats[t * 2 + 1] = rsqrtf(var + 1e-5f);
    }
}

// ---------------- Kernel 3a: conv + K/V build -> ws (fp8) ----------------
// grid (16 mi-rows, 32 batches), 512 threads. K stored [b][m][64], V stored [b][d][256].
__global__ __launch_bounds__(512) void k_kvb(
    const float* __restrict__ x, const float* __restrict__ Wdw, const float* __restrict__ bdw,
    const float* __restrict__ Wk, const float* __restrict__ bk,
    const float* __restrict__ Wv, const float* __restrict__ bv,
    unsigned char* __restrict__ Kg, unsigned char* __restrict__ Vg)
{
    __shared__ __align__(16) unsigned char Y[16 * 72];
    const int mi = blockIdx.x, b = blockIdx.y;
    const int t = threadIdx.x, w = t >> 6, lane = t & 63;
    const int quad = lane >> 4, l = lane & 15;
    const float* xb = x + b * 262144;

    const int s2l = lane & 3, mjl = lane >> 2;
    #pragma unroll
    for (int ci = 0; ci < 8; ++ci) {
        int c = w * 8 + ci;
        float wd0 = Wdw[c * 16 + 0 + s2l];
        float wd1 = Wdw[c * 16 + 4 + s2l];
        float wd2 = Wdw[c * 16 + 8 + s2l];
        float wd3 = Wdw[c * 16 + 12 + s2l];
        const float* xr = xb + c * 4096 + mi * 256;
        float acc = xr[lane] * wd0;
        acc = fmaf(xr[64 + lane],  wd1, acc);
        acc = fmaf(xr[128 + lane], wd2, acc);
        acc = fmaf(xr[192 + lane], wd3, acc);
        acc += __shfl_xor(acc, 1);
        acc += __shfl_xor(acc, 2);
        if (s2l == 0) Y[mjl * 72 + c] = f2fp8(acc + bdw[c]);
    }
    __syncthreads();

    long ya0 = *(const long*)(Y + l * 72 + quad * 8);
    long ya1 = *(const long*)(Y + l * 72 + 32 + quad * 8);
    if (w < 4) {
        int e4 = w;
        long f0 = packrow8(Wk + (e4 * 16 + l) * 64 + quad * 8);
        long f1 = packrow8(Wk + (e4 * 16 + l) * 64 + 32 + quad * 8);
        float bb = bk[e4 * 16 + l];
        f32x4 c = { bb, bb, bb, bb };
        c = MFMA8(ya0, f0, c);
        c = MFMA8(ya1, f1, c);
        unsigned char* kd = Kg + b * 16384 + (mi * 16 + quad * 4) * 64 + e4 * 16 + l;
        #pragma unroll
        for (int r = 0; r < 4; ++r) kd[r * 64] = f2fp8(c[r]);
    } else {
        int d4 = w - 4;
        long f0 = packrow8(Wv + (d4 * 16 + l) * 64 + quad * 8);
        long f1 = packrow8(Wv + (d4 * 16 + l) * 64 + 32 + quad * 8);
        f32x4 c = { bv[d4 * 16 + quad * 4 + 0], bv[d4 * 16 + quad * 4 + 1],
                    bv[d4 * 16 + quad * 4 + 2], bv[d4 * 16 + quad * 4 + 3] };
        c = MFMA8(f0, ya0, c);
        c = MFMA8(f1, ya1, c);
        unsigned char* vd = Vg + b * 16384 + (d4 * 16 + quad * 4) * 256 + mi * 16 + l;
        #pragma unroll
        for (int r = 0; r < 4; ++r) vd[r * 256] = f2fp8(c[r]);
    }
}

// ---------------- Kernel 3b: per-tile attention (fp8 MFMA) ----------------
// grid (64 tiles, 32 batches), 512 threads = 8 waves, one 64-query tile per block.
// LDS: Kf [256][80] @0 | Vt [64][272] @20480 | XS [64][72] @37888 | QF [64][72] @42496
//      PS 8x[16][40] @47104 | TS [64][72] @52224   total 56832 B
__global__ __launch_bounds__(512, 4) void k_attn2(
    const float* __restrict__ x, const float* __restrict__ Wq, const float* __restrict__ bq,
    const float* __restrict__ Wo, const float* __restrict__ bo, const float* __restrict__ Bb,
    const float* __restrict__ stats, const unsigned char* __restrict__ Kg,
    const unsigned char* __restrict__ Vg, float* __restrict__ outp)
{
    __shared__ __align__(16) long smem8[7104];
    unsigned char* S = (unsigned char*)smem8;
    unsigned char* Kf = S;                 // [256][80]
    unsigned char* Vt = S + 20480;         // [64][272]
    unsigned char* XS = S + 37888;         // [64][72]
    unsigned char* QF = S + 42496;         // [64][72]
    unsigned char* TS = S + 52224;         // [64][72]
    const int tile = blockIdx.x, b = blockIdx.y;
    const int t = threadIdx.x, w = t >> 6, lane = t & 63;
    const int quad = lane >> 4, l = lane & 15;
    unsigned char* PS = S + 47104 + w * 640;
    const int n0 = tile * 64;
    const float mu = stats[2 * b], rstd = stats[2 * b + 1];
    const float* xb = x + b * 262144;
    const float SCALE = 0.17677669529663687f;

    // ---- stage K, V tiles from ws (fp8) ----
    const unsigned char* Kgb = Kg + b * 16384;
    const unsigned char* Vgb = Vg + b * 16384;
    #pragma unroll
    for (int r = 0; r < 2; ++r) {
        int idx = t + 512 * r;
        int m = idx >> 2, c16 = (idx & 3) * 16;
        *(uint4*)(Kf + m * 80 + c16) = *(const uint4*)(Kgb + m * 64 + c16);
        int d = idx >> 4, e16 = (idx & 15) * 16;
        *(uint4*)(Vt + d * 272 + e16) = *(const uint4*)(Vgb + d * 256 + e16);
    }
    // ---- stage normalized x tile -> XS[n][c] fp8 ----
    #pragma unroll
    for (int ci = 0; ci < 8; ++ci) {
        int c = w * 8 + ci;
        float v = (xb[c * 4096 + n0 + lane] - mu) * rstd;
        XS[lane * 72 + c] = f2fp8(v);
    }
    // ---- weight fragments ----
    const int rtq = w >> 1, ct0 = (w & 1) * 2;
    long wqF[4], woF[4];
    float bqr[2], bor[2];
    #pragma unroll
    for (int i = 0; i < 2; ++i) {
        #pragma unroll
        for (int st = 0; st < 2; ++st) {
            wqF[i * 2 + st] = packrow8(Wq + ((ct0 + i) * 16 + l) * 64 + st * 32 + quad * 8);
            woF[i * 2 + st] = packrow8(Wo + ((ct0 + i) * 16 + l) * 64 + st * 32 + quad * 8);
        }
        bqr[i] = bq[(ct0 + i) * 16 + l];
        bor[i] = bo[(ct0 + i) * 16 + l];
    }
    __syncthreads();

    // ---- Q-gen via MFMA -> QF fp8 ----
    {
        long xa0 = *(const long*)(XS + (rtq * 16 + l) * 72 + quad * 8);
        long xa1 = *(const long*)(XS + (rtq * 16 + l) * 72 + 32 + quad * 8);
        #pragma unroll
        for (int i = 0; i < 2; ++i) {
            f32x4 c = { bqr[i], bqr[i], bqr[i], bqr[i] };
            c = MFMA8(xa0, wqF[i * 2 + 0], c);
            c = MFMA8(xa1, wqF[i * 2 + 1], c);
            unsigned char* qd = QF + (rtq * 16 + quad * 4) * 72 + (ct0 + i) * 16 + l;
            #pragma unroll
            for (int r = 0; r < 4; ++r) qd[r * 72] = f2fp8(c[r]);
        }
    }
    __syncthreads();

    // ---- attention: wave = (h = w&1, nq = w>>1), 16 q-rows, 256 keys ----
    const int h = w & 1, nq = w >> 1;
    long qa = *(const long*)(QF + (nq * 16 + l) * 72 + h * 32 + quad * 8);
    f32x4 O0 = { 0, 0, 0, 0 }, O1 = { 0, 0, 0, 0 };
    float Lp[4] = { 0, 0, 0, 0 };
    const float* Bbase = Bb + h * 1048576 + (n0 + nq * 16 + quad * 4) * 256;

    #pragma unroll 2
    for (int mc = 0; mc < 8; ++mc) {
        float Bv[2][4];
        #pragma unroll
        for (int sub = 0; sub < 2; ++sub)
            #pragma unroll
            for (int r = 0; r < 4; ++r)
                Bv[sub][r] = Bbase[r * 256 + (mc * 2 + sub) * 16 + l];
        long kb0 = *(const long*)(Kf + ((mc * 2 + 0) * 16 + l) * 80 + h * 32 + quad * 8);
        long kb1 = *(const long*)(Kf + ((mc * 2 + 1) * 16 + l) * 80 + h * 32 + quad * 8);
        #pragma unroll
        for (int sub = 0; sub < 2; ++sub) {
            f32x4 sc = { 0, 0, 0, 0 };
            sc = MFMA8(qa, sub ? kb1 : kb0, sc);
            unsigned char* pw = PS + (quad * 4) * 40 + sub * 16 + l;
            #pragma unroll
            for (int r = 0; r < 4; ++r) {
                float p = __expf(fmaf(sc[r], SCALE, Bv[sub][r]));
                Lp[r] += p;
                pw[r * 40] = f2fp8(p);
            }
        }
        long pa  = *(const long*)(PS + l * 40 + quad * 8);
        long vb0 = *(const long*)(Vt + (h * 32 + l) * 272 + mc * 32 + quad * 8);
        long vb1 = *(const long*)(Vt + (h * 32 + 16 + l) * 272 + mc * 32 + quad * 8);
        O0 = MFMA8(pa, vb0, O0);
        O1 = MFMA8(pa, vb1, O1);
    }
    #pragma unroll
    for (int r = 0; r < 4; ++r) {
        #pragma unroll
        for (int d = 1; d < 16; d <<= 1) Lp[r] += __shfl_xor(Lp[r], d);
    }
    {
        unsigned char* td = TS + (nq * 16 + quad * 4) * 72 + h * 32 + l;
        #pragma unroll
        for (int r = 0; r < 4; ++r) {
            float inv = 1.0f / Lp[r];
            td[r * 72]      = f2fp8(O0[r] * inv);
            td[r * 72 + 16] = f2fp8(O1[r] * inv);
        }
    }
    __syncthreads();

    // ---- out-proj + bias + residual ----
    {
        long ta0 = *(const long*)(TS + (rtq * 16 + l) * 72 + quad * 8);
        long ta1 = *(const long*)(TS + (rtq * 16 + l) * 72 + 32 + quad * 8);
        float* ob = outp + b * 262144 + tile * 4096;
        const float* xr2 = xb + tile * 4096;
        #pragma unroll
        for (int i = 0; i < 2; ++i) {
            f32x4 c = { bor[i], bor[i], bor[i], bor[i] };
            c = MFMA8(ta0, woF[i * 2 + 0], c);
            c = MFMA8(ta1, woF[i * 2 + 1], c);
            #pragma unroll
            for (int r = 0; r < 4; ++r) {
                int off = (rtq * 16 + quad * 4 + r) * 64 + (ct0 + i) * 16 + l;
                ob[off] = c[r] + xr2[off];
            }
        }
    }
}

// ---------------- Fallback (round-3 fused kernel, used if ws too small) ----------------
__global__ __launch_bounds__(512) void k_fused(
    const float* __restrict__ x, const float* __restrict__ Wdw, const float* __restrict__ bdw,
    const float* __restrict__ Wq, const float* __restrict__ bq,
    const float* __restrict__ Wk, const float* __restrict__ bk,
    const float* __restrict__ Wv, const float* __restrict__ bv,
    const float* __restrict__ Wo, const float* __restrict__ bo,
    const float* __restrict__ Bb, const float* __restrict__ stats,
    float* __restrict__ outp)
{
    __shared__ long smem8[6784];
    unsigned char* S = (unsigned char*)smem8;
    unsigned char* Kf = S;
    unsigned char* Vt = S + 18432;
    unsigned char* Y  = S + 35328;
    unsigned char* XS = S + 35328;
    unsigned char* QF = S + 35328 + 4608;
    unsigned char* TS = S + 35328 + 14336;

    const int tg = blockIdx.x, b = blockIdx.y;
    const int t = threadIdx.x, w = t >> 6, lane = t & 63;
    const int quad = lane >> 4, l = lane & 15;
    unsigned char* PS = S + 35328 + 9216 + w * 640;

    const float mu = stats[2 * b], rstd = stats[2 * b + 1];
    const float* xb = x + b * 262144;
    const float SCALE = 0.17677669529663687f;

    long wkF[8], wvF[8];
    #pragma unroll
    for (int e4 = 0; e4 < 4; ++e4)
        #pragma unroll
        for (int st = 0; st < 2; ++st) {
            wkF[e4 * 2 + st] = packrow8(Wk + (e4 * 16 + l) * 64 + st * 32 + quad * 8);
            wvF[e4 * 2 + st] = packrow8(Wv + (e4 * 16 + l) * 64 + st * 32 + quad * 8);
        }
    const int rtq = w >> 1, ct0 = (w & 1) * 2;
    long wqF[4], woF[4];
    #pragma unroll
    for (int i = 0; i < 2; ++i)
        #pragma unroll
        for (int st = 0; st < 2; ++st) {
            wqF[i * 2 + st] = packrow8(Wq + ((ct0 + i) * 16 + l) * 64 + st * 32 + quad * 8);
            woF[i * 2 + st] = packrow8(Wo + ((ct0 + i) * 16 + l) * 64 + st * 32 + quad * 8);
        }
    float bkr[4], bvr[4][4], bqr[2], bor[2];
    #pragma unroll
    for (int e4 = 0; e4 < 4; ++e4) bkr[e4] = bk[e4 * 16 + l];
    #pragma unroll
    for (int d4 = 0; d4 < 4; ++d4)
        #pragma unroll
        for (int r = 0; r < 4; ++r) bvr[d4][r] = bv[d4 * 16 + quad * 4 + r];
    #pragma unroll
    for (int i = 0; i < 2; ++i) { bqr[i] = bq[(ct0 + i) * 16 + l]; bor[i] = bo[(ct0 + i) * 16 + l]; }

    {
        const int s2l = lane & 3, mjl = lane >> 2;
        for (int ci = 0; ci < 8; ++ci) {
            int c = w * 8 + ci;
            float wd0 = Wdw[c * 16 + 0 + s2l];
            float wd1 = Wdw[c * 16 + 4 + s2l];
            float wd2 = Wdw[c * 16 + 8 + s2l];
            float wd3 = Wdw[c * 16 + 12 + s2l];
            float bdc = bdw[c];
            #pragma unroll 4
            for (int mi = 0; mi < 16; ++mi) {
                const float* xr = xb + c * 4096 + mi * 256;
                float acc = xr[lane] * wd0;
                acc = fmaf(xr[64 + lane],  wd1, acc);
                acc = fmaf(xr[128 + lane], wd2, acc);
                acc = fmaf(xr[192 + lane], wd3, acc);
                acc += __shfl_xor(acc, 1);
                acc += __shfl_xor(acc, 2);
                if (s2l == 0) Y[(mi * 16 + mjl) * 72 + c] = f2fp8(acc + bdc);
            }
        }
    }
    __syncthreads();

    #pragma unroll
    for (int i = 0; i < 2; ++i) {
        int rt = w * 2 + i;
        long ya0 = *(const long*)(Y + (rt * 16 + l) * 72 + quad * 8);
        long ya1 = *(const long*)(Y + (rt * 16 + l) * 72 + 32 + quad * 8);
        #pragma unroll
        for (int e4 = 0; e4 < 4; ++e4) {
            f32x4 c = { bkr[e4], bkr[e4], bkr[e4], bkr[e4] };
            c = MFMA8(ya0, wkF[e4 * 2 + 0], c);
            c = MFMA8(ya1, wkF[e4 * 2 + 1], c);
            unsigned char* kd = Kf + (rt * 16 + quad * 4) * 72 + e4 * 16 + l;
            #pragma unroll
            for (int r = 0; r < 4; ++r) kd[r * 72] = f2fp8(c[r]);
        }
        #pragma unroll
        for (int d4 = 0; d4 < 4; ++d4) {
            f32x4 c = { bvr[d4][0], bvr[d4][1], bvr[d4][2], bvr[d4][3] };
            c = MFMA8(wvF[d4 * 2 + 0], ya0, c);
            c = MFMA8(wvF[d4 * 2 + 1], ya1, c);
            unsigned char* vd = Vt + (d4 * 16 + quad * 4) * 264 + rt * 16 + l;
            #pragma unroll
            for (int r = 0; r < 4; ++r) vd[r * 264] = f2fp8(c[r]);
        }
    }
    __syncthreads();

    const int h = w & 1, nq = w >> 1;

    for (int tile = 0; tile < 8; ++tile) {
        const int tidx = tg * 8 + tile, n0 = tidx * 64;

        for (int ci = 0; ci < 8; ++ci) {
            int c = w * 8 + ci;
            float v = (xb[c * 4096 + n0 + lane] - mu) * rstd;
            XS[lane * 72 + c] = f2fp8(v);
        }
        __syncthreads();

        {
            long xa0 = *(const long*)(XS + (rtq * 16 + l) * 72 + quad * 8);
            long xa1 = *(const long*)(XS + (rtq * 16 + l) * 72 + 32 + quad * 8);
            #pragma unroll
            for (int i = 0; i < 2; ++i) {
                f32x4 c = { bqr[i], bqr[i], bqr[i], bqr[i] };
                c = MFMA8(xa0, wqF[i * 2 + 0], c);
                c = MFMA8(xa1, wqF[i * 2 + 1], c);
                unsigned char* qd = QF + (rtq * 16 + quad * 4) * 72 + (ct0 + i) * 16 + l;
                #pragma unroll
                for (int r = 0; r < 4; ++r) qd[r * 72] = f2fp8(c[r]);
            }
        }
        __syncthreads();

        long qa = *(const long*)(QF + (nq * 16 + l) * 72 + h * 32 + quad * 8);
        f32x4 O0 = { 0, 0, 0, 0 }, O1 = { 0, 0, 0, 0 };
        float Lp[4] = { 0, 0, 0, 0 };
        const float* Bbase = Bb + h * 1048576 + (n0 + nq * 16 + quad * 4) * 256;

        #pragma unroll 2
        for (int mc = 0; mc < 8; ++mc) {
            #pragma unroll
            for (int sub = 0; sub < 2; ++sub) {
                int mt = mc * 2 + sub;
                long kb = *(const long*)(Kf + (mt * 16 + l) * 72 + h * 32 + quad * 8);
                f32x4 sc = { 0, 0, 0, 0 };
                sc = MFMA8(qa, kb, sc);
                unsigned char* pw = PS + (quad * 4) * 40 + sub * 16 + l;
                #pragma unroll
                for (int r = 0; r < 4; ++r) {
                    float p = __expf(fmaf(sc[r], SCALE, Bbase[r * 256 + mt * 16 + l]));
                    Lp[r] += p;
                    pw[r * 40] = f2fp8(p);
                }
            }
            long pa  = *(const long*)(PS + l * 40 + quad * 8);
            long vb0 = *(const long*)(Vt + (h * 32 + l) * 264 + mc * 32 + quad * 8);
            long vb1 = *(const long*)(Vt + (h * 32 + 16 + l) * 264 + mc * 32 + quad * 8);
            O0 = MFMA8(pa, vb0, O0);
            O1 = MFMA8(pa, vb1, O1);
        }
        #pragma unroll
        for (int r = 0; r < 4; ++r) {
            #pragma unroll
            for (int d = 1; d < 16; d <<= 1) Lp[r] += __shfl_xor(Lp[r], d);
        }
        {
            unsigned char* td = TS + (nq * 16 + quad * 4) * 72 + h * 32 + l;
            #pragma unroll
            for (int r = 0; r < 4; ++r) {
                float inv = 1.0f / Lp[r];
                td[r * 72]      = f2fp8(O0[r] * inv);
                td[r * 72 + 16] = f2fp8(O1[r] * inv);
            }
        }
        __syncthreads();

        {
            long ta0 = *(const long*)(TS + (rtq * 16 + l) * 72 + quad * 8);
            long ta1 = *(const long*)(TS + (rtq * 16 + l) * 72 + 32 + quad * 8);
            float* ob = outp + b * 262144 + tidx * 4096;
            const float* xr2 = xb + tidx * 4096;
            #pragma unroll
            for (int i = 0; i < 2; ++i) {
                f32x4 c = { bor[i], bor[i], bor[i], bor[i] };
                c = MFMA8(ta0, woF[i * 2 + 0], c);
                c = MFMA8(ta1, woF[i * 2 + 1], c);
                #pragma unroll
                for (int r = 0; r < 4; ++r) {
                    int off = (rtq * 16 + quad * 4 + r) * 64 + (ct0 + i) * 16 + l;
                    ob[off] = c[r] + xr2[off];
                }
            }
        }
        __syncthreads();
    }
}

extern "C" void kernel_launch(void* const* d_in, const int* in_sizes, int n_in,
                              void* d_out, int out_size, void* d_ws, size_t ws_size,
                              hipStream_t stream) {
    (void)in_sizes; (void)n_in; (void)out_size;
    const float* x   = (const float*)d_in[0];
    const float* Wdw = (const float*)d_in[1];
    const float* bdw = (const float*)d_in[2];
    const float* Wq  = (const float*)d_in[3];
    const float* bq  = (const float*)d_in[4];
    const float* Wk  = (const float*)d_in[5];
    const float* bk  = (const float*)d_in[6];
    const float* Wv  = (const float*)d_in[7];
    const float* bv  = (const float*)d_in[8];
    const float* Wo  = (const float*)d_in[9];
    const float* bo  = (const float*)d_in[10];
    const float* Bb  = (const float*)d_in[11];
    float* outp = (float*)d_out;

    float* ws    = (float*)d_ws;
    float* part  = ws;            // 1024 f32
    float* stats = ws + 1024;     // 64 f32
    unsigned char* Kg = (unsigned char*)d_ws + 8192;      // 512 KB
    unsigned char* Vg = (unsigned char*)d_ws + 8192 + 524288;  // 512 KB

    k_ln_part<<<dim3(16, 32), 256, 0, stream>>>(x, part);
    k_ln_fin<<<1, 64, 0, stream>>>(part, stats);
    if (ws_size >= (size_t)(8192 + 2 * 524288)) {
        k_kvb<<<dim3(16, 32), 512, 0, stream>>>(x, Wdw, bdw, Wk, bk, Wv, bv, Kg, Vg);
        k_attn2<<<dim3(64, 32), 512, 0, stream>>>(x, Wq, bq, Wo, bo, Bb, stats, Kg, Vg, outp);
    } else {
        k_fused<<<dim3(8, 32), 512, 0, stream>>>(x, Wdw, bdw, Wq, bq, Wk, bk, Wv, bv,
                                                 Wo, bo, Bb, stats, outp);
    }
}

// Round 5
// 145.068 us; speedup vs baseline: 1.6567x; 1.1489x over previous
//
#include <hip/hip_runtime.h>

typedef float f32x4 __attribute__((ext_vector_type(4)));

#define MFMA8(a, b, c) __builtin_amdgcn_mfma_f32_16x16x32_fp8_fp8((long)(a), (long)(b), (c), 0, 0, 0)

__device__ __forceinline__ unsigned char f2fp8(float v) {
    int pk = __builtin_amdgcn_cvt_pk_fp8_f32(v, v, 0, false);
    return (unsigned char)(pk & 0xff);
}
__device__ __forceinline__ long packrow8(const float* p) {
    f32x4 a = *(const f32x4*)(p);
    f32x4 b = *(const f32x4*)(p + 4);
    int lo = __builtin_amdgcn_cvt_pk_fp8_f32(a.x, a.y, 0, false);
    lo = __builtin_amdgcn_cvt_pk_fp8_f32(a.z, a.w, lo, true);
    int hi = __builtin_amdgcn_cvt_pk_fp8_f32(b.x, b.y, 0, false);
    hi = __builtin_amdgcn_cvt_pk_fp8_f32(b.z, b.w, hi, true);
    return (long)(((unsigned long)(unsigned int)hi << 32) | (unsigned int)lo);
}
__device__ __forceinline__ int pack4(const float* p) {
    int v = __builtin_amdgcn_cvt_pk_fp8_f32(p[0], p[1], 0, false);
    return __builtin_amdgcn_cvt_pk_fp8_f32(p[2], p[3], v, true);
}

// ---------------- Kernel 1 (fallback only): LayerNorm partial sums ----------------
__global__ __launch_bounds__(256) void k_ln_part(const float* __restrict__ x,
                                                 float* __restrict__ part) {
    const int chunk = blockIdx.x, b = blockIdx.y, t = threadIdx.x;
    const float4* p = (const float4*)(x + b * 262144 + chunk * 16384);
    float s = 0.f, ss = 0.f;
    #pragma unroll
    for (int r = 0; r < 16; ++r) {
        float4 v = p[r * 256 + t];
        s  += v.x + v.y + v.z + v.w;
        ss += v.x * v.x + v.y * v.y + v.z * v.z + v.w * v.w;
    }
    #pragma unroll
    for (int off = 32; off > 0; off >>= 1) {
        s  += __shfl_down(s, off);
        ss += __shfl_down(ss, off);
    }
    __shared__ float sm[8];
    int wv = t >> 6;
    if ((t & 63) == 0) { sm[wv * 2] = s; sm[wv * 2 + 1] = ss; }
    __syncthreads();
    if (t == 0) {
        float S  = sm[0] + sm[2] + sm[4] + sm[6];
        float SS = sm[1] + sm[3] + sm[5] + sm[7];
        part[(b * 16 + chunk) * 2]     = S;
        part[(b * 16 + chunk) * 2 + 1] = SS;
    }
}

// ---------------- Kernel 2 (fallback only): LayerNorm finalize ----------------
__global__ void k_ln_fin(const float* __restrict__ part, float* __restrict__ stats) {
    int t = threadIdx.x;
    if (t < 32) {
        float S = 0.f, SS = 0.f;
        for (int k = 0; k < 16; ++k) {
            S  += part[(t * 16 + k) * 2];
            SS += part[(t * 16 + k) * 2 + 1];
        }
        const float inv = 1.0f / 262144.0f;
        float mu  = S * inv;
        float var = SS * inv - mu * mu;
        stats[t * 2]     = mu;
        stats[t * 2 + 1] = rsqrtf(var + 1e-5f);
    }
}

// ---------------- Kernel A: conv + K/V build + LN partial sums ----------------
// grid (16 mi-rows, 32 batches), 512 threads. K stored [b][m][64], V stored [b][d][256].
// Each block reads a disjoint 1/16th of x[b] (all 64 channels x 256 hw) -> LN partials free.
__global__ __launch_bounds__(512) void k_kvb2(
    const float* __restrict__ x, const float* __restrict__ Wdw, const float* __restrict__ bdw,
    const float* __restrict__ Wk, const float* __restrict__ bk,
    const float* __restrict__ Wv, const float* __restrict__ bv,
    unsigned char* __restrict__ Kg, unsigned char* __restrict__ Vg,
    float* __restrict__ part)
{
    __shared__ __align__(16) unsigned char Y[16 * 72];
    __shared__ float sm[16];
    const int mi = blockIdx.x, b = blockIdx.y;
    const int t = threadIdx.x, w = t >> 6, lane = t & 63;
    const int quad = lane >> 4, l = lane & 15;
    const float* xb = x + b * 262144;

    const int s2l = lane & 3, mjl = lane >> 2;
    float s = 0.f, ss = 0.f;
    #pragma unroll
    for (int ci = 0; ci < 8; ++ci) {
        int c = w * 8 + ci;
        float wd0 = Wdw[c * 16 + 0 + s2l];
        float wd1 = Wdw[c * 16 + 4 + s2l];
        float wd2 = Wdw[c * 16 + 8 + s2l];
        float wd3 = Wdw[c * 16 + 12 + s2l];
        const float* xr = xb + c * 4096 + mi * 256;
        float v0 = xr[lane], v1 = xr[64 + lane], v2 = xr[128 + lane], v3 = xr[192 + lane];
        s  += v0 + v1 + v2 + v3;
        ss += v0 * v0 + v1 * v1 + v2 * v2 + v3 * v3;
        float acc = v0 * wd0;
        acc = fmaf(v1, wd1, acc);
        acc = fmaf(v2, wd2, acc);
        acc = fmaf(v3, wd3, acc);
        acc += __shfl_xor(acc, 1);
        acc += __shfl_xor(acc, 2);
        if (s2l == 0) Y[mjl * 72 + c] = f2fp8(acc + bdw[c]);
    }
    #pragma unroll
    for (int off = 32; off > 0; off >>= 1) {
        s  += __shfl_down(s, off);
        ss += __shfl_down(ss, off);
    }
    if (lane == 0) { sm[w * 2] = s; sm[w * 2 + 1] = ss; }
    __syncthreads();
    if (t == 0) {
        float S = 0.f, SS = 0.f;
        #pragma unroll
        for (int i = 0; i < 8; ++i) { S += sm[i * 2]; SS += sm[i * 2 + 1]; }
        part[(b * 16 + mi) * 2]     = S;
        part[(b * 16 + mi) * 2 + 1] = SS;
    }

    long ya0 = *(const long*)(Y + l * 72 + quad * 8);
    long ya1 = *(const long*)(Y + l * 72 + 32 + quad * 8);
    if (w < 4) {
        int e4 = w;
        long f0 = packrow8(Wk + (e4 * 16 + l) * 64 + quad * 8);
        long f1 = packrow8(Wk + (e4 * 16 + l) * 64 + 32 + quad * 8);
        float bb = bk[e4 * 16 + l];
        f32x4 c = { bb, bb, bb, bb };
        c = MFMA8(ya0, f0, c);
        c = MFMA8(ya1, f1, c);
        unsigned char* kd = Kg + b * 16384 + (mi * 16 + quad * 4) * 64 + e4 * 16 + l;
        #pragma unroll
        for (int r = 0; r < 4; ++r) kd[r * 64] = f2fp8(c[r]);
    } else {
        int d4 = w - 4;
        long f0 = packrow8(Wv + (d4 * 16 + l) * 64 + quad * 8);
        long f1 = packrow8(Wv + (d4 * 16 + l) * 64 + 32 + quad * 8);
        f32x4 c = { bv[d4 * 16 + quad * 4 + 0], bv[d4 * 16 + quad * 4 + 1],
                    bv[d4 * 16 + quad * 4 + 2], bv[d4 * 16 + quad * 4 + 3] };
        c = MFMA8(f0, ya0, c);
        c = MFMA8(f1, ya1, c);
        unsigned char* vd = Vg + b * 16384 + (d4 * 16 + quad * 4) * 256 + mi * 16 + l;
        #pragma unroll
        for (int r = 0; r < 4; ++r) vd[r * 256] = f2fp8(c[r]);
    }
}

// ---------------- Kernel B: LN finalize + Wq/Wo fp8 pre-pack ----------------
// 1 block, 256 threads.
__global__ void k_prep(const float* __restrict__ part, const float* __restrict__ Wq,
                       const float* __restrict__ Wo, float* __restrict__ stats,
                       unsigned char* __restrict__ Wq8, unsigned char* __restrict__ Wo8)
{
    int t = threadIdx.x;
    if (t < 32) {
        float S = 0.f, SS = 0.f;
        for (int k = 0; k < 16; ++k) {
            S  += part[(t * 16 + k) * 2];
            SS += part[(t * 16 + k) * 2 + 1];
        }
        const float inv = 1.0f / 262144.0f;
        float mu  = S * inv;
        float var = SS * inv - mu * mu;
        stats[t * 2]     = mu;
        stats[t * 2 + 1] = rsqrtf(var + 1e-5f);
    }
    // pack 4096 f32 -> 4096 fp8 bytes each; thread t handles 16 consecutive values
    {
        float f[16];
        #pragma unroll
        for (int g = 0; g < 4; ++g) *(f32x4*)&f[g * 4] = *(const f32x4*)(Wq + t * 16 + g * 4);
        uint4 o;
        o.x = pack4(&f[0]); o.y = pack4(&f[4]); o.z = pack4(&f[8]); o.w = pack4(&f[12]);
        *(uint4*)(Wq8 + t * 16) = o;
    }
    {
        float f[16];
        #pragma unroll
        for (int g = 0; g < 4; ++g) *(f32x4*)&f[g * 4] = *(const f32x4*)(Wo + t * 16 + g * 4);
        uint4 o;
        o.x = pack4(&f[0]); o.y = pack4(&f[4]); o.z = pack4(&f[8]); o.w = pack4(&f[12]);
        *(uint4*)(Wo8 + t * 16) = o;
    }
}

// ---------------- Kernel C: per-tile attention (fp8 MFMA) ----------------
// grid (64 tiles, 32 batches), 512 threads = 8 waves, one 64-query tile per block.
// LDS: Kf [256][80] @0 | Vt [64][272] @20480 | XS/TS union [64][72] @37888
//      QF [64][72] @42496 | PS 8x[16][40] @47104   total 52224 B -> 3 blocks/CU
__global__ __launch_bounds__(512, 6) void k_attn3(
    const float* __restrict__ x, const unsigned char* __restrict__ Wq8,
    const float* __restrict__ bq, const unsigned char* __restrict__ Wo8,
    const float* __restrict__ bo, const float* __restrict__ Bb,
    const float* __restrict__ stats, const unsigned char* __restrict__ Kg,
    const unsigned char* __restrict__ Vg, float* __restrict__ outp)
{
    __shared__ __align__(16) long smem8[6528];
    unsigned char* S = (unsigned char*)smem8;
    unsigned char* Kf = S;                 // [256][80]
    unsigned char* Vt = S + 20480;         // [64][272]
    unsigned char* XS = S + 37888;         // [64][72]  (aliased by TS after Q-gen)
    unsigned char* QF = S + 42496;         // [64][72]
    unsigned char* TS = S + 37888;         // alias of XS
    const int tile = blockIdx.x, b = blockIdx.y;
    const int t = threadIdx.x, w = t >> 6, lane = t & 63;
    const int quad = lane >> 4, l = lane & 15;
    unsigned char* PS = S + 47104 + w * 640;
    const int n0 = tile * 64;
    const float mu = stats[2 * b], rstd = stats[2 * b + 1];
    const float* xb = x + b * 262144;
    const float SCALE = 0.17677669529663687f;

    // ---- stage K, V tiles from ws (fp8) ----
    const unsigned char* Kgb = Kg + b * 16384;
    const unsigned char* Vgb = Vg + b * 16384;
    #pragma unroll
    for (int r = 0; r < 2; ++r) {
        int idx = t + 512 * r;
        int m = idx >> 2, c16 = (idx & 3) * 16;
        *(uint4*)(Kf + m * 80 + c16) = *(const uint4*)(Kgb + m * 64 + c16);
        int d = idx >> 4, e16 = (idx & 15) * 16;
        *(uint4*)(Vt + d * 272 + e16) = *(const uint4*)(Vgb + d * 256 + e16);
    }
    // ---- stage normalized x tile -> XS[n][c] fp8 ----
    #pragma unroll
    for (int ci = 0; ci < 8; ++ci) {
        int c = w * 8 + ci;
        float v = (xb[c * 4096 + n0 + lane] - mu) * rstd;
        XS[lane * 72 + c] = f2fp8(v);
    }
    // ---- weight fragments from pre-packed fp8 ----
    const int rtq = w >> 1, ct0 = (w & 1) * 2;
    long wqF[4], woF[4];
    float bqr[2], bor[2];
    #pragma unroll
    for (int i = 0; i < 2; ++i) {
        #pragma unroll
        for (int st = 0; st < 2; ++st) {
            wqF[i * 2 + st] = *(const long*)(Wq8 + ((ct0 + i) * 16 + l) * 64 + st * 32 + quad * 8);
            woF[i * 2 + st] = *(const long*)(Wo8 + ((ct0 + i) * 16 + l) * 64 + st * 32 + quad * 8);
        }
        bqr[i] = bq[(ct0 + i) * 16 + l];
        bor[i] = bo[(ct0 + i) * 16 + l];
    }
    __syncthreads();

    // ---- Q-gen via MFMA -> QF fp8 ----
    {
        long xa0 = *(const long*)(XS + (rtq * 16 + l) * 72 + quad * 8);
        long xa1 = *(const long*)(XS + (rtq * 16 + l) * 72 + 32 + quad * 8);
        #pragma unroll
        for (int i = 0; i < 2; ++i) {
            f32x4 c = { bqr[i], bqr[i], bqr[i], bqr[i] };
            c = MFMA8(xa0, wqF[i * 2 + 0], c);
            c = MFMA8(xa1, wqF[i * 2 + 1], c);
            unsigned char* qd = QF + (rtq * 16 + quad * 4) * 72 + (ct0 + i) * 16 + l;
            #pragma unroll
            for (int r = 0; r < 4; ++r) qd[r * 72] = f2fp8(c[r]);
        }
    }
    __syncthreads();

    // ---- attention: wave = (h = w&1, nq = w>>1), 16 q-rows, 256 keys ----
    const int h = w & 1, nq = w >> 1;
    long qa = *(const long*)(QF + (nq * 16 + l) * 72 + h * 32 + quad * 8);
    f32x4 O0 = { 0, 0, 0, 0 }, O1 = { 0, 0, 0, 0 };
    float Lp[4] = { 0, 0, 0, 0 };
    const float* Bbase = Bb + h * 1048576 + (n0 + nq * 16 + quad * 4) * 256;

    // software-pipelined B loads: Bv holds biases for current mc
    float Bv[2][4];
    #pragma unroll
    for (int sub = 0; sub < 2; ++sub)
        #pragma unroll
        for (int r = 0; r < 4; ++r)
            Bv[sub][r] = Bbase[r * 256 + sub * 16 + l];

    #pragma unroll 2
    for (int mc = 0; mc < 8; ++mc) {
        float Bn[2][4];
        if (mc < 7) {
            #pragma unroll
            for (int sub = 0; sub < 2; ++sub)
                #pragma unroll
                for (int r = 0; r < 4; ++r)
                    Bn[sub][r] = Bbase[r * 256 + (mc * 2 + 2 + sub) * 16 + l];
        }
        long kb0 = *(const long*)(Kf + ((mc * 2 + 0) * 16 + l) * 80 + h * 32 + quad * 8);
        long kb1 = *(const long*)(Kf + ((mc * 2 + 1) * 16 + l) * 80 + h * 32 + quad * 8);
        #pragma unroll
        for (int sub = 0; sub < 2; ++sub) {
            f32x4 sc = { 0, 0, 0, 0 };
            sc = MFMA8(qa, sub ? kb1 : kb0, sc);
            unsigned char* pw = PS + (quad * 4) * 40 + sub * 16 + l;
            #pragma unroll
            for (int r = 0; r < 4; ++r) {
                float p = __expf(fmaf(sc[r], SCALE, Bv[sub][r]));
                Lp[r] += p;
                pw[r * 40] = f2fp8(p);
            }
        }
        long pa  = *(const long*)(PS + l * 40 + quad * 8);
        long vb0 = *(const long*)(Vt + (h * 32 + l) * 272 + mc * 32 + quad * 8);
        long vb1 = *(const long*)(Vt + (h * 32 + 16 + l) * 272 + mc * 32 + quad * 8);
        O0 = MFMA8(pa, vb0, O0);
        O1 = MFMA8(pa, vb1, O1);
        #pragma unroll
        for (int sub = 0; sub < 2; ++sub)
            #pragma unroll
            for (int r = 0; r < 4; ++r)
                Bv[sub][r] = Bn[sub][r];
    }
    #pragma unroll
    for (int r = 0; r < 4; ++r) {
        #pragma unroll
        for (int d = 1; d < 16; d <<= 1) Lp[r] += __shfl_xor(Lp[r], d);
    }
    {
        unsigned char* td = TS + (nq * 16 + quad * 4) * 72 + h * 32 + l;
        #pragma unroll
        for (int r = 0; r < 4; ++r) {
            float inv = 1.0f / Lp[r];
            td[r * 72]      = f2fp8(O0[r] * inv);
            td[r * 72 + 16] = f2fp8(O1[r] * inv);
        }
    }
    __syncthreads();

    // ---- out-proj + bias + residual ----
    {
        long ta0 = *(const long*)(TS + (rtq * 16 + l) * 72 + quad * 8);
        long ta1 = *(const long*)(TS + (rtq * 16 + l) * 72 + 32 + quad * 8);
        float* ob = outp + b * 262144 + tile * 4096;
        const float* xr2 = xb + tile * 4096;
        #pragma unroll
        for (int i = 0; i < 2; ++i) {
            f32x4 c = { bor[i], bor[i], bor[i], bor[i] };
            c = MFMA8(ta0, woF[i * 2 + 0], c);
            c = MFMA8(ta1, woF[i * 2 + 1], c);
            #pragma unroll
            for (int r = 0; r < 4; ++r) {
                int off = (rtq * 16 + quad * 4 + r) * 64 + (ct0 + i) * 16 + l;
                ob[off] = c[r] + xr2[off];
            }
        }
    }
}

// ---------------- Fallback (round-3 fused kernel, used if ws too small) ----------------
__global__ __launch_bounds__(512) void k_fused(
    const float* __restrict__ x, const float* __restrict__ Wdw, const float* __restrict__ bdw,
    const float* __restrict__ Wq, const float* __restrict__ bq,
    const float* __restrict__ Wk, const float* __restrict__ bk,
    const float* __restrict__ Wv, const float* __restrict__ bv,
    const float* __restrict__ Wo, const float* __restrict__ bo,
    const float* __restrict__ Bb, const float* __restrict__ stats,
    float* __restrict__ outp)
{
    __shared__ long smem8[6784];
    unsigned char* S = (unsigned char*)smem8;
    unsigned char* Kf = S;
    unsigned char* Vt = S + 18432;
    unsigned char* Y  = S + 35328;
    unsigned char* XS = S + 35328;
    unsigned char* QF = S + 35328 + 4608;
    unsigned char* TS = S + 35328 + 14336;

    const int tg = blockIdx.x, b = blockIdx.y;
    const int t = threadIdx.x, w = t >> 6, lane = t & 63;
    const int quad = lane >> 4, l = lane & 15;
    unsigned char* PS = S + 35328 + 9216 + w * 640;

    const float mu = stats[2 * b], rstd = stats[2 * b + 1];
    const float* xb = x + b * 262144;
    const float SCALE = 0.17677669529663687f;

    long wkF[8], wvF[8];
    #pragma unroll
    for (int e4 = 0; e4 < 4; ++e4)
        #pragma unroll
        for (int st = 0; st < 2; ++st) {
            wkF[e4 * 2 + st] = packrow8(Wk + (e4 * 16 + l) * 64 + st * 32 + quad * 8);
            wvF[e4 * 2 + st] = packrow8(Wv + (e4 * 16 + l) * 64 + st * 32 + quad * 8);
        }
    const int rtq = w >> 1, ct0 = (w & 1) * 2;
    long wqF[4], woF[4];
    #pragma unroll
    for (int i = 0; i < 2; ++i)
        #pragma unroll
        for (int st = 0; st < 2; ++st) {
            wqF[i * 2 + st] = packrow8(Wq + ((ct0 + i) * 16 + l) * 64 + st * 32 + quad * 8);
            woF[i * 2 + st] = packrow8(Wo + ((ct0 + i) * 16 + l) * 64 + st * 32 + quad * 8);
        }
    float bkr[4], bvr[4][4], bqr[2], bor[2];
    #pragma unroll
    for (int e4 = 0; e4 < 4; ++e4) bkr[e4] = bk[e4 * 16 + l];
    #pragma unroll
    for (int d4 = 0; d4 < 4; ++d4)
        #pragma unroll
        for (int r = 0; r < 4; ++r) bvr[d4][r] = bv[d4 * 16 + quad * 4 + r];
    #pragma unroll
    for (int i = 0; i < 2; ++i) { bqr[i] = bq[(ct0 + i) * 16 + l]; bor[i] = bo[(ct0 + i) * 16 + l]; }

    {
        const int s2l = lane & 3, mjl = lane >> 2;
        for (int ci = 0; ci < 8; ++ci) {
            int c = w * 8 + ci;
            float wd0 = Wdw[c * 16 + 0 + s2l];
            float wd1 = Wdw[c * 16 + 4 + s2l];
            float wd2 = Wdw[c * 16 + 8 + s2l];
            float wd3 = Wdw[c * 16 + 12 + s2l];
            float bdc = bdw[c];
            #pragma unroll 4
            for (int mi = 0; mi < 16; ++mi) {
                const float* xr = xb + c * 4096 + mi * 256;
                float acc = xr[lane] * wd0;
                acc = fmaf(xr[64 + lane],  wd1, acc);
                acc = fmaf(xr[128 + lane], wd2, acc);
                acc = fmaf(xr[192 + lane], wd3, acc);
                acc += __shfl_xor(acc, 1);
                acc += __shfl_xor(acc, 2);
                if (s2l == 0) Y[(mi * 16 + mjl) * 72 + c] = f2fp8(acc + bdc);
            }
        }
    }
    __syncthreads();

    #pragma unroll
    for (int i = 0; i < 2; ++i) {
        int rt = w * 2 + i;
        long ya0 = *(const long*)(Y + (rt * 16 + l) * 72 + quad * 8);
        long ya1 = *(const long*)(Y + (rt * 16 + l) * 72 + 32 + quad * 8);
        #pragma unroll
        for (int e4 = 0; e4 < 4; ++e4) {
            f32x4 c = { bkr[e4], bkr[e4], bkr[e4], bkr[e4] };
            c = MFMA8(ya0, wkF[e4 * 2 + 0], c);
            c = MFMA8(ya1, wkF[e4 * 2 + 1], c);
            unsigned char* kd = Kf + (rt * 16 + quad * 4) * 72 + e4 * 16 + l;
            #pragma unroll
            for (int r = 0; r < 4; ++r) kd[r * 72] = f2fp8(c[r]);
        }
        #pragma unroll
        for (int d4 = 0; d4 < 4; ++d4) {
            f32x4 c = { bvr[d4][0], bvr[d4][1], bvr[d4][2], bvr[d4][3] };
            c = MFMA8(wvF[d4 * 2 + 0], ya0, c);
            c = MFMA8(wvF[d4 * 2 + 1], ya1, c);
            unsigned char* vd = Vt + (d4 * 16 + quad * 4) * 264 + rt * 16 + l;
            #pragma unroll
            for (int r = 0; r < 4; ++r) vd[r * 264] = f2fp8(c[r]);
        }
    }
    __syncthreads();

    const int h = w & 1, nq = w >> 1;

    for (int tile = 0; tile < 8; ++tile) {
        const int tidx = tg * 8 + tile, n0 = tidx * 64;

        for (int ci = 0; ci < 8; ++ci) {
            int c = w * 8 + ci;
            float v = (xb[c * 4096 + n0 + lane] - mu) * rstd;
            XS[lane * 72 + c] = f2fp8(v);
        }
        __syncthreads();

        {
            long xa0 = *(const long*)(XS + (rtq * 16 + l) * 72 + quad * 8);
            long xa1 = *(const long*)(XS + (rtq * 16 + l) * 72 + 32 + quad * 8);
            #pragma unroll
            for (int i = 0; i < 2; ++i) {
                f32x4 c = { bqr[i], bqr[i], bqr[i], bqr[i] };
                c = MFMA8(xa0, wqF[i * 2 + 0], c);
                c = MFMA8(xa1, wqF[i * 2 + 1], c);
                unsigned char* qd = QF + (rtq * 16 + quad * 4) * 72 + (ct0 + i) * 16 + l;
                #pragma unroll
                for (int r = 0; r < 4; ++r) qd[r * 72] = f2fp8(c[r]);
            }
        }
        __syncthreads();

        long qa = *(const long*)(QF + (nq * 16 + l) * 72 + h * 32 + quad * 8);
        f32x4 O0 = { 0, 0, 0, 0 }, O1 = { 0, 0, 0, 0 };
        float Lp[4] = { 0, 0, 0, 0 };
        const float* Bbase = Bb + h * 1048576 + (n0 + nq * 16 + quad * 4) * 256;

        #pragma unroll 2
        for (int mc = 0; mc < 8; ++mc) {
            #pragma unroll
            for (int sub = 0; sub < 2; ++sub) {
                int mt = mc * 2 + sub;
                long kb = *(const long*)(Kf + (mt * 16 + l) * 72 + h * 32 + quad * 8);
                f32x4 sc = { 0, 0, 0, 0 };
                sc = MFMA8(qa, kb, sc);
                unsigned char* pw = PS + (quad * 4) * 40 + sub * 16 + l;
                #pragma unroll
                for (int r = 0; r < 4; ++r) {
                    float p = __expf(fmaf(sc[r], SCALE, Bbase[r * 256 + mt * 16 + l]));
                    Lp[r] += p;
                    pw[r * 40] = f2fp8(p);
                }
            }
            long pa  = *(const long*)(PS + l * 40 + quad * 8);
            long vb0 = *(const long*)(Vt + (h * 32 + l) * 264 + mc * 32 + quad * 8);
            long vb1 = *(const long*)(Vt + (h * 32 + 16 + l) * 264 + mc * 32 + quad * 8);
            O0 = MFMA8(pa, vb0, O0);
            O1 = MFMA8(pa, vb1, O1);
        }
        #pragma unroll
        for (int r = 0; r < 4; ++r) {
            #pragma unroll
            for (int d = 1; d < 16; d <<= 1) Lp[r] += __shfl_xor(Lp[r], d);
        }
        {
            unsigned char* td = TS + (nq * 16 + quad * 4) * 72 + h * 32 + l;
            #pragma unroll
            for (int r = 0; r < 4; ++r) {
                float inv = 1.0f / Lp[r];
                td[r * 72]      = f2fp8(O0[r] * inv);
                td[r * 72 + 16] = f2fp8(O1[r] * inv);
            }
        }
        __syncthreads();

        {
            long ta0 = *(const long*)(TS + (rtq * 16 + l) * 72 + quad * 8);
            long ta1 = *(const long*)(TS + (rtq * 16 + l) * 72 + 32 + quad * 8);
            float* ob = outp + b * 262144 + tidx * 4096;
            const float* xr2 = xb + tidx * 4096;
            #pragma unroll
            for (int i = 0; i < 2; ++i) {
                f32x4 c = { bor[i], bor[i], bor[i], bor[i] };
                c = MFMA8(ta0, woF[i * 2 + 0], c);
                c = MFMA8(ta1, woF[i * 2 + 1], c);
                #pragma unroll
                for (int r = 0; r < 4; ++r) {
                    int off = (rtq * 16 + quad * 4 + r) * 64 + (ct0 + i) * 16 + l;
                    ob[off] = c[r] + xr2[off];
                }
            }
        }
        __syncthreads();
    }
}

extern "C" void kernel_launch(void* const* d_in, const int* in_sizes, int n_in,
                              void* d_out, int out_size, void* d_ws, size_t ws_size,
                              hipStream_t stream) {
    (void)in_sizes; (void)n_in; (void)out_size;
    const float* x   = (const float*)d_in[0];
    const float* Wdw = (const float*)d_in[1];
    const float* bdw = (const float*)d_in[2];
    const float* Wq  = (const float*)d_in[3];
    const float* bq  = (const float*)d_in[4];
    const float* Wk  = (const float*)d_in[5];
    const float* bk  = (const float*)d_in[6];
    const float* Wv  = (const float*)d_in[7];
    const float* bv  = (const float*)d_in[8];
    const float* Wo  = (const float*)d_in[9];
    const float* bo  = (const float*)d_in[10];
    const float* Bb  = (const float*)d_in[11];
    float* outp = (float*)d_out;

    float* ws    = (float*)d_ws;
    float* part  = ws;                                     // 1024 f32 @ 0
    float* stats = ws + 1024;                              // 64 f32  @ 4096
    unsigned char* Wq8 = (unsigned char*)d_ws + 8192;      // 4 KB
    unsigned char* Wo8 = (unsigned char*)d_ws + 12288;     // 4 KB
    unsigned char* Kg  = (unsigned char*)d_ws + 16384;     // 512 KB
    unsigned char* Vg  = Kg + 524288;                      // 512 KB

    if (ws_size >= (size_t)(16384 + 2 * 524288)) {
        k_kvb2<<<dim3(16, 32), 512, 0, stream>>>(x, Wdw, bdw, Wk, bk, Wv, bv, Kg, Vg, part);
        k_prep<<<1, 256, 0, stream>>>(part, Wq, Wo, stats, Wq8, Wo8);
        k_attn3<<<dim3(64, 32), 512, 0, stream>>>(x, Wq8, bq, Wo8, bo, Bb, stats, Kg, Vg, outp);
    } else {
        k_ln_part<<<dim3(16, 32), 256, 0, stream>>>(x, part);
        k_ln_fin<<<1, 64, 0, stream>>>(part, stats);
        k_fused<<<dim3(8, 32), 512, 0, stream>>>(x, Wdw, bdw, Wq, bq, Wk, bk, Wv, bv,
                                                 Wo, bo, Bb, stats, outp);
    }
}